// Round 5
// baseline (143.512 us; speedup 1.0000x reference)
//
#include <hip/hip_runtime.h>
#include <math.h>

#define BB   8
#define CC   256
#define HH   56
#define WW   56
#define KK   3
#define MIDN 51
#define NTAP (KK*KK)          // 9
#define CKK  (CC*NTAP)        // 2304
#define HW   (HH*WW)          // 3136
#define NCH  4                // channel chunks for sf reduction
#define CPC  (CC/NCH)         // 64 channels per chunk
#define PBLK 13               // ceil(3136/256)
#define NCPB 4                // channels per ddf block (sf-reuse factor)
#define TILE 3364             // 58*58 halo tile

// ============ K1: fused sf partial-reduction + pooled-mean partials ============
// grid: BB*NCH*PBLK = 416 blocks, 256 threads (256 consecutive pixels).
__global__ __launch_bounds__(256) void k_sfpool(const float* __restrict__ x,
                                                const float* __restrict__ ws,
                                                float* __restrict__ partial,
                                                float* __restrict__ poolpart) {
    int blk = blockIdx.x;
    int pb = blk % PBLK;
    int tmp = blk / PBLK;
    int chunk = tmp % NCH;
    int b = tmp / NCH;
    int t = threadIdx.x;
    int wave = t >> 6, lane = t & 63;
    __shared__ float wss[NTAP][CPC];
    __shared__ float wsum[4][CPC];
    for (int idx = t; idx < NTAP * CPC; idx += 256) {
        int n = idx / CPC, c = idx - n * CPC;
        wss[n][c] = ws[n * CC + chunk * CPC + c];
    }
    __syncthreads();
    int p = pb * 256 + t;
    bool act = (p < HW);
    float acc[NTAP];
    #pragma unroll
    for (int n = 0; n < NTAP; ++n) acc[n] = 0.f;
    const float* xp = x + ((size_t)(b * CC + chunk * CPC)) * HW + p;
    for (int c = 0; c < CPC; ++c) {
        float xv = act ? xp[(size_t)c * HW] : 0.f;
        #pragma unroll
        for (int n = 0; n < NTAP; ++n) acc[n] += xv * wss[n][c];
        float s = xv;
        s += __shfl_down(s, 32, 64);
        s += __shfl_down(s, 16, 64);
        s += __shfl_down(s, 8, 64);
        s += __shfl_down(s, 4, 64);
        s += __shfl_down(s, 2, 64);
        s += __shfl_down(s, 1, 64);
        if (lane == 0) wsum[wave][c] = s;
    }
    __syncthreads();
    if (t < CPC) {
        float psum = wsum[0][t] + wsum[1][t] + wsum[2][t] + wsum[3][t];
        poolpart[((size_t)((b * NCH + chunk) * PBLK + pb)) * CPC + t] = psum;
    }
    if (act) {
        float* pp = partial + ((size_t)((b * NCH + chunk) * NTAP)) * HW + p;
        #pragma unroll
        for (int n = 0; n < NTAP; ++n) pp[(size_t)n * HW] = acc[n];
    }
}

// ============ K2: multi-role — blocks 0..63: MLP+cf ; blocks 64..167: sf reduce+norm ============
#define MLPBLK (BB*8)                 // 64 (MLP keeps its own 8x32-channel split)
#define W2CHUNK (32*NTAP*MIDN)        // 14688 floats per 32-channel chunk
__global__ __launch_bounds__(256) void k_mlp_sfB(const float* __restrict__ poolpart,
                                                 const float* __restrict__ w1,
                                                 const float* __restrict__ b1,
                                                 const float* __restrict__ w2,
                                                 const float* __restrict__ b2,
                                                 const float* __restrict__ fn_std,
                                                 const float* __restrict__ partial,
                                                 const float* __restrict__ bs,
                                                 float* __restrict__ cf,
                                                 float* __restrict__ sf) {
    __shared__ float smem[W2CHUNK + 256 + 64 + 32 * NTAP];  // 61.2 KB
    float* w2s = smem;                    // [14688]
    float* ps  = smem + W2CHUNK;          // [256]
    float* y1  = ps + 256;                // [64] (51 used)
    float* y2s = y1 + 64;                 // [288]
    int blk = blockIdx.x;
    int t = threadIdx.x;
    if (blk < MLPBLK) {
        int b = blk >> 3, mchunk = blk & 7;
        int c0 = mchunk * 32;
        const float4* w2v = (const float4*)(w2 + (size_t)mchunk * W2CHUNK);
        float4* w2s4 = (float4*)w2s;
        for (int i = t; i < W2CHUNK / 4; i += 256) w2s4[i] = w2v[i];
        {
            // pooled mean for all 256 channels of batch b; NCH=4 x CPC=64 layout
            int chunkp = t >> 6, cl = t & 63;
            float s = 0.f;
            const float* pp = poolpart + ((size_t)(b * NCH + chunkp) * PBLK) * CPC + cl;
            #pragma unroll
            for (int pb = 0; pb < PBLK; ++pb) s += pp[pb * CPC];
            ps[t] = s * (1.0f / HW);
        }
        __syncthreads();
        if (t < MIDN) {
            float acc = b1[t];
            const float* wr = w1 + t * CC;
            for (int c2 = 0; c2 < CC; ++c2) acc += ps[c2] * wr[c2];
            y1[t] = fmaxf(acc, 0.f);
        }
        __syncthreads();
        #pragma unroll
        for (int base = 0; base < 512; base += 256) {
            int idx = base + t;                       // idx = cl*9+q
            if (idx < 32 * NTAP) {
                float acc = b2[c0 * NTAP + idx];
                const float* r = w2s + idx * MIDN;
                #pragma unroll 3
                for (int m = 0; m < MIDN; ++m) acc += y1[m] * r[m];
                y2s[idx] = acc;
            }
        }
        __syncthreads();
        if (t < 32) {
            int c = c0 + t;
            float y2[NTAP];
            #pragma unroll
            for (int q = 0; q < NTAP; ++q) y2[q] = y2s[t * NTAP + q];
            float mean = 0.f;
            #pragma unroll
            for (int q = 0; q < NTAP; ++q) mean += y2[q];
            mean *= (1.f / NTAP);
            float var = 0.f;
            #pragma unroll
            for (int q = 0; q < NTAP; ++q) { float d = y2[q] - mean; var += d * d; }
            float inv = 1.f / (sqrtf(var * (1.f / (NTAP - 1))) + 1e-10f);
            #pragma unroll
            for (int q = 0; q < NTAP; ++q) {
                int idx = c * NTAP + q;
                cf[(size_t)b * CKK + idx] = (y2[q] - mean) * inv * fn_std[idx];
            }
        }
    } else {
        int sblk = blk - MLPBLK;                 // 0..103
        int b = sblk / PBLK, pb = sblk % PBLK;
        int p = pb * 256 + t;
        if (p >= HW) return;
        float acc[NTAP];
        #pragma unroll
        for (int n = 0; n < NTAP; ++n) acc[n] = bs[n];
        const float* pp = partial + ((size_t)(b * NCH)) * NTAP * HW + p;
        for (int chunk = 0; chunk < NCH; ++chunk)
            #pragma unroll
            for (int n = 0; n < NTAP; ++n)
                acc[n] += pp[((size_t)(chunk * NTAP + n)) * HW];
        float mean = 0.f;
        #pragma unroll
        for (int n = 0; n < NTAP; ++n) mean += acc[n];
        mean *= (1.f / NTAP);
        float var = 0.f;
        #pragma unroll
        for (int n = 0; n < NTAP; ++n) { float d = acc[n] - mean; var += d * d; }
        float inv = 0.47140452079103173f /       // GAIN/K = sqrt(2)/3
                    (sqrtf(var * (1.f / (NTAP - 1))) + 1e-10f);
        #pragma unroll
        for (int n = 0; n < NTAP; ++n)
            sf[((size_t)(b * NTAP + n)) * HW + p] = (acc[n] - mean) * inv;
    }
}

// ============ K3: DDF apply — NCPB=4 channels per block; sf loaded once per pixel ============
// grid: BB * CC/NCPB = 512 blocks. LDS: 4 halo tiles = 53.8 KB -> 2 blocks/CU.
__global__ __launch_bounds__(256) void k_ddf(const float* __restrict__ x,
                                             const float* __restrict__ cf,
                                             const float* __restrict__ sf,
                                             float* __restrict__ out) {
    int blk = blockIdx.x;
    int b = blk / (CC / NCPB), cg = blk % (CC / NCPB);
    int c0 = cg * NCPB;
    int t = threadIdx.x;
    __shared__ float xt[NCPB][TILE];
    for (int idx = t; idx < NCPB * TILE; idx += 256) ((float*)xt)[idx] = 0.f;
    __syncthreads();
    // stage 4 contiguous planes with float4 loads (4*3136 floats contiguous)
    const float4* xp4 = (const float4*)(x + ((size_t)(b * CC + c0)) * HW);
    for (int i4 = t; i4 < NCPB * HW / 4; i4 += 256) {
        float4 v = xp4[i4];
        int k = i4 / (HW / 4);                 // plane
        int rem4 = i4 - k * (HW / 4);          // float4 index within plane
        int r = rem4 / (WW / 4);               // row
        int col = 4 * (rem4 - r * (WW / 4));   // col (multiple of 4)
        float* d = &xt[k][(r + 1) * 58 + col + 1];
        d[0] = v.x; d[1] = v.y; d[2] = v.z; d[3] = v.w;
    }
    float cf9[NCPB][NTAP];
    const float* cfp = cf + (size_t)b * CKK + c0 * NTAP;
    #pragma unroll
    for (int k = 0; k < NCPB; ++k)
        #pragma unroll
        for (int n = 0; n < NTAP; ++n) cf9[k][n] = cfp[k * NTAP + n];
    __syncthreads();
    const float* sfb = sf + (size_t)b * NTAP * HW;
    float* op = out + ((size_t)(b * CC + c0)) * HW;
    for (int idx = t; idx < HW; idx += 256) {
        int i = idx / WW, j = idx - i * WW;
        float s9[NTAP];
        #pragma unroll
        for (int n = 0; n < NTAP; ++n) s9[n] = sfb[(size_t)n * HW + idx];
        float acc[NCPB];
        #pragma unroll
        for (int k = 0; k < NCPB; ++k) acc[k] = 0.f;
        #pragma unroll
        for (int u = 0; u < KK; ++u)
            #pragma unroll
            for (int v = 0; v < KK; ++v) {
                int n = u * KK + v;
                int o = (i + u) * 58 + (j + v);
                #pragma unroll
                for (int k = 0; k < NCPB; ++k)
                    acc[k] += xt[k][o] * (cf9[k][n] * s9[n]);
            }
        #pragma unroll
        for (int k = 0; k < NCPB; ++k) op[(size_t)k * HW + idx] = acc[k];
    }
}

extern "C" void kernel_launch(void* const* d_in, const int* in_sizes, int n_in,
                              void* d_out, int out_size, void* d_ws, size_t ws_size,
                              hipStream_t stream) {
    const float* x      = (const float*)d_in[0];
    const float* w1     = (const float*)d_in[1];
    const float* b1     = (const float*)d_in[2];
    const float* w2     = (const float*)d_in[3];
    const float* b2     = (const float*)d_in[4];
    const float* ws     = (const float*)d_in[5];
    const float* bs     = (const float*)d_in[6];
    const float* fn_std = (const float*)d_in[7];
    float* out = (float*)d_out;

    float* wsf      = (float*)d_ws;
    float* cf       = wsf;                         // BB*CKK           = 18432
    float* sf       = cf + 18432;                  // BB*NTAP*HW       = 225792
    float* poolpart = sf + 225792;                 // BB*NCH*PBLK*CPC  = 26624
    float* partial  = poolpart + 26624;            // BB*NCH*NTAP*HW   = 903168

    k_sfpool<<<BB * NCH * PBLK, 256, 0, stream>>>(x, ws, partial, poolpart);
    k_mlp_sfB<<<MLPBLK + BB * PBLK, 256, 0, stream>>>(poolpart, w1, b1, w2, b2,
                                                      fn_std, partial, bs, cf, sf);
    k_ddf<<<BB * (CC / NCPB), 256, 0, stream>>>(x, cf, sf, out);
}

// Round 6
// 126.472 us; speedup vs baseline: 1.1347x; 1.1347x over previous
//
#include <hip/hip_runtime.h>
#include <math.h>

#define BB   8
#define CC   256
#define HH   56
#define WW   56
#define KK   3
#define MIDN 51
#define NTAP (KK*KK)          // 9
#define CKK  (CC*NTAP)        // 2304
#define HW   (HH*WW)          // 3136
#define NCH  8                // channel chunks for sf reduction
#define CPC  (CC/NCH)         // 32 channels per chunk
#define PBLK 13               // ceil(3136/256)
#define NCPB 2                // channels per ddf block (sf-reuse factor)
#define XSTR 33               // LDS tile stride: bank (p+c)%32, 2 lanes/bank = free

// ============ K1: fused sf partial-reduction + pooled-mean partials ============
// grid: BB*NCH*PBLK = 832 blocks, 256 threads. NO cross-lane ops: x staged in
// LDS (transposed, stride-33), pool = LDS column sums, sf = LDS row dots.
__global__ __launch_bounds__(256) void k_sfpool(const float* __restrict__ x,
                                                const float* __restrict__ ws,
                                                float* __restrict__ partial,
                                                float* __restrict__ poolpart) {
    int blk = blockIdx.x;
    int pb = blk % PBLK;
    int tmp = blk / PBLK;
    int chunk = tmp % NCH;
    int b = tmp / NCH;
    int t = threadIdx.x;
    __shared__ float xs[256 * XSTR];      // xs[p][c] = xs[p*33+c], 33.8 KB
    __shared__ float wss[NTAP][CPC];
    __shared__ float psum[8][CPC];
    for (int idx = t; idx < NTAP * CPC; idx += 256) {
        int n = idx / CPC, c = idx - n * CPC;
        wss[n][c] = ws[n * CC + chunk * CPC + c];
    }
    // stage tile: iteration k reads channel k, pixel t (coalesced 256B/wave)
    const float* xb = x + ((size_t)(b * CC + chunk * CPC)) * HW + pb * 256;
    bool act = (pb * 256 + t < HW);
    #pragma unroll 4
    for (int c = 0; c < CPC; ++c) {
        float v = act ? xb[(size_t)c * HW + t] : 0.f;
        xs[t * XSTR + c] = v;
    }
    __syncthreads();
    // pooled partial: thread (seg=t>>5, c=t&31) sums 32 pixels of channel c
    {
        int c = t & 31, seg = t >> 5;
        float s = 0.f;
        #pragma unroll 8
        for (int i = 0; i < 32; ++i) s += xs[(seg * 32 + i) * XSTR + c];
        psum[seg][c] = s;
    }
    // sf einsum: thread t = pixel p, dot over 32 channels from LDS
    float acc[NTAP];
    #pragma unroll
    for (int n = 0; n < NTAP; ++n) acc[n] = 0.f;
    #pragma unroll 4
    for (int c = 0; c < CPC; ++c) {
        float xv = xs[t * XSTR + c];
        #pragma unroll
        for (int n = 0; n < NTAP; ++n) acc[n] += xv * wss[n][c];
    }
    if (act) {
        float* pp = partial + ((size_t)((b * NCH + chunk) * NTAP)) * HW + pb * 256 + t;
        #pragma unroll
        for (int n = 0; n < NTAP; ++n) pp[(size_t)n * HW] = acc[n];
    }
    __syncthreads();
    if (t < CPC) {
        float tot = 0.f;
        #pragma unroll
        for (int seg = 0; seg < 8; ++seg) tot += psum[seg][t];
        poolpart[((size_t)((b * NCH + chunk) * PBLK + pb)) * CPC + t] = tot;
    }
}

// ============ K2: multi-role — blocks 0..63: MLP+cf ; blocks 64..167: sf reduce+norm ============
#define MLPBLK (BB*NCH)               // 64
#define W2CHUNK (CPC*NTAP*MIDN)       // 14688 floats per 32-channel chunk
__global__ __launch_bounds__(256) void k_mlp_sfB(const float* __restrict__ poolpart,
                                                 const float* __restrict__ w1,
                                                 const float* __restrict__ b1,
                                                 const float* __restrict__ w2,
                                                 const float* __restrict__ b2,
                                                 const float* __restrict__ fn_std,
                                                 const float* __restrict__ partial,
                                                 const float* __restrict__ bs,
                                                 float* __restrict__ cf,
                                                 float* __restrict__ sf) {
    __shared__ float smem[W2CHUNK + 256 + 64 + CPC * NTAP];  // 61.2 KB
    float* w2s = smem;                    // [14688]
    float* ps  = smem + W2CHUNK;          // [256]
    float* y1  = ps + 256;                // [64] (51 used)
    float* y2s = y1 + 64;                 // [288]
    int blk = blockIdx.x;
    int t = threadIdx.x;
    if (blk < MLPBLK) {
        int b = blk >> 3, chunk = blk & 7;
        int c0 = chunk * CPC;
        const float4* w2v = (const float4*)(w2 + (size_t)chunk * W2CHUNK);
        float4* w2s4 = (float4*)w2s;
        for (int i = t; i < W2CHUNK / 4; i += 256) w2s4[i] = w2v[i];
        {
            int chunkp = t >> 5, cl = t & 31;
            float s = 0.f;
            const float* pp = poolpart + ((size_t)(b * NCH + chunkp) * PBLK) * CPC + cl;
            #pragma unroll
            for (int pb = 0; pb < PBLK; ++pb) s += pp[pb * CPC];
            ps[t] = s * (1.0f / HW);
        }
        __syncthreads();
        if (t < MIDN) {
            float acc = b1[t];
            const float* wr = w1 + t * CC;
            for (int c2 = 0; c2 < CC; ++c2) acc += ps[c2] * wr[c2];
            y1[t] = fmaxf(acc, 0.f);
        }
        __syncthreads();
        #pragma unroll
        for (int base = 0; base < 512; base += 256) {
            int idx = base + t;                       // idx = cl*9+q
            if (idx < CPC * NTAP) {
                float acc = b2[c0 * NTAP + idx];
                const float* r = w2s + idx * MIDN;
                #pragma unroll 3
                for (int m = 0; m < MIDN; ++m) acc += y1[m] * r[m];
                y2s[idx] = acc;
            }
        }
        __syncthreads();
        if (t < CPC) {
            int c = c0 + t;
            float y2[NTAP];
            #pragma unroll
            for (int q = 0; q < NTAP; ++q) y2[q] = y2s[t * NTAP + q];
            float mean = 0.f;
            #pragma unroll
            for (int q = 0; q < NTAP; ++q) mean += y2[q];
            mean *= (1.f / NTAP);
            float var = 0.f;
            #pragma unroll
            for (int q = 0; q < NTAP; ++q) { float d = y2[q] - mean; var += d * d; }
            float inv = 1.f / (sqrtf(var * (1.f / (NTAP - 1))) + 1e-10f);
            #pragma unroll
            for (int q = 0; q < NTAP; ++q) {
                int idx = c * NTAP + q;
                cf[(size_t)b * CKK + idx] = (y2[q] - mean) * inv * fn_std[idx];
            }
        }
    } else {
        int sblk = blk - MLPBLK;                 // 0..103
        int b = sblk / PBLK, pb = sblk % PBLK;
        int p = pb * 256 + t;
        if (p >= HW) return;
        float acc[NTAP];
        #pragma unroll
        for (int n = 0; n < NTAP; ++n) acc[n] = bs[n];
        const float* pp = partial + ((size_t)(b * NCH)) * NTAP * HW + p;
        for (int chunk = 0; chunk < NCH; ++chunk)
            #pragma unroll
            for (int n = 0; n < NTAP; ++n)
                acc[n] += pp[((size_t)(chunk * NTAP + n)) * HW];
        float mean = 0.f;
        #pragma unroll
        for (int n = 0; n < NTAP; ++n) mean += acc[n];
        mean *= (1.f / NTAP);
        float var = 0.f;
        #pragma unroll
        for (int n = 0; n < NTAP; ++n) { float d = acc[n] - mean; var += d * d; }
        float inv = 0.47140452079103173f /       // GAIN/K = sqrt(2)/3
                    (sqrtf(var * (1.f / (NTAP - 1))) + 1e-10f);
        #pragma unroll
        for (int n = 0; n < NTAP; ++n)
            sf[((size_t)(b * NTAP + n)) * HW + p] = (acc[n] - mean) * inv;
    }
}

// ============ K3: DDF apply — NCPB=2 channels per block; sf loaded once per pixel ============
// grid: BB * CC/NCPB = 1024 blocks. LDS: 2 halo tiles = 26.9 KB -> 4 blocks/CU.
__global__ __launch_bounds__(256) void k_ddf(const float* __restrict__ x,
                                             const float* __restrict__ cf,
                                             const float* __restrict__ sf,
                                             float* __restrict__ out) {
    int blk = blockIdx.x;
    int b = blk / (CC / NCPB), cg = blk % (CC / NCPB);
    int c0 = cg * NCPB;
    int t = threadIdx.x;
    __shared__ float xt[NCPB][58 * 58];
    for (int idx = t; idx < NCPB * 58 * 58; idx += 256) ((float*)xt)[idx] = 0.f;
    __syncthreads();
    const float* xp = x + ((size_t)(b * CC + c0)) * HW;
    for (int idx = t; idx < HW; idx += 256) {
        int r = idx / WW, col = idx - r * WW;
        int o = (r + 1) * 58 + col + 1;
        xt[0][o] = xp[idx];
        xt[1][o] = xp[HW + idx];
    }
    float cf9[NCPB][NTAP];
    const float* cfp = cf + (size_t)b * CKK + c0 * NTAP;
    #pragma unroll
    for (int k = 0; k < NCPB; ++k)
        #pragma unroll
        for (int n = 0; n < NTAP; ++n) cf9[k][n] = cfp[k * NTAP + n];
    __syncthreads();
    const float* sfb = sf + (size_t)b * NTAP * HW;
    float* op = out + ((size_t)(b * CC + c0)) * HW;
    for (int idx = t; idx < HW; idx += 256) {
        int i = idx / WW, j = idx - i * WW;
        float s9[NTAP];
        #pragma unroll
        for (int n = 0; n < NTAP; ++n) s9[n] = sfb[(size_t)n * HW + idx];
        float acc0 = 0.f, acc1 = 0.f;
        #pragma unroll
        for (int u = 0; u < KK; ++u)
            #pragma unroll
            for (int v = 0; v < KK; ++v) {
                int n = u * KK + v;
                int o = (i + u) * 58 + (j + v);
                acc0 += xt[0][o] * (cf9[0][n] * s9[n]);
                acc1 += xt[1][o] * (cf9[1][n] * s9[n]);
            }
        op[idx] = acc0;
        op[HW + idx] = acc1;
    }
}

extern "C" void kernel_launch(void* const* d_in, const int* in_sizes, int n_in,
                              void* d_out, int out_size, void* d_ws, size_t ws_size,
                              hipStream_t stream) {
    const float* x      = (const float*)d_in[0];
    const float* w1     = (const float*)d_in[1];
    const float* b1     = (const float*)d_in[2];
    const float* w2     = (const float*)d_in[3];
    const float* b2     = (const float*)d_in[4];
    const float* ws     = (const float*)d_in[5];
    const float* bs     = (const float*)d_in[6];
    const float* fn_std = (const float*)d_in[7];
    float* out = (float*)d_out;

    float* wsf      = (float*)d_ws;
    float* cf       = wsf;                         // BB*CKK           = 18432
    float* sf       = cf + 18432;                  // BB*NTAP*HW       = 225792
    float* poolpart = sf + 225792;                 // BB*NCH*PBLK*CPC  = 26624
    float* partial  = poolpart + 26624;            // BB*NCH*NTAP*HW   = 1806336

    k_sfpool<<<BB * NCH * PBLK, 256, 0, stream>>>(x, ws, partial, poolpart);
    k_mlp_sfB<<<MLPBLK + BB * PBLK, 256, 0, stream>>>(poolpart, w1, b1, w2, b2,
                                                      fn_std, partial, bs, cf, sf);
    k_ddf<<<BB * (CC / NCPB), 256, 0, stream>>>(x, cf, sf, out);
}

// Round 7
// 123.932 us; speedup vs baseline: 1.1580x; 1.0205x over previous
//
#include <hip/hip_runtime.h>
#include <math.h>

#define BB   8
#define CC   256
#define HH   56
#define WW   56
#define KK   3
#define MIDN 51
#define NTAP (KK*KK)          // 9
#define CKK  (CC*NTAP)        // 2304
#define HW   (HH*WW)          // 3136
#define NCH  8                // channel chunks for sf reduction
#define CPC  (CC/NCH)         // 32 channels per chunk
#define PBLK 13               // ceil(3136/256)
#define NCPB 4                // channels per ddf block
#define TILE 3364             // 58*58 halo tile
#define XSTR 33               // LDS tile stride: bank (p+c)%32, 2 lanes/bank = free

// ============ K1: fused sf partial-reduction + pooled-mean partials ============
// grid: BB*NCH*PBLK = 832 blocks, 256 threads. NO cross-lane ops: x staged in
// LDS (transposed, stride-33), pool = LDS column sums, sf = LDS row dots.
__global__ __launch_bounds__(256) void k_sfpool(const float* __restrict__ x,
                                                const float* __restrict__ ws,
                                                float* __restrict__ partial,
                                                float* __restrict__ poolpart) {
    int blk = blockIdx.x;
    int pb = blk % PBLK;
    int tmp = blk / PBLK;
    int chunk = tmp % NCH;
    int b = tmp / NCH;
    int t = threadIdx.x;
    __shared__ float xs[256 * XSTR];      // xs[p][c] = xs[p*33+c], 33.8 KB
    __shared__ float wss[NTAP][CPC];
    __shared__ float psum[8][CPC];
    for (int idx = t; idx < NTAP * CPC; idx += 256) {
        int n = idx / CPC, c = idx - n * CPC;
        wss[n][c] = ws[n * CC + chunk * CPC + c];
    }
    const float* xb = x + ((size_t)(b * CC + chunk * CPC)) * HW + pb * 256;
    bool act = (pb * 256 + t < HW);
    #pragma unroll 4
    for (int c = 0; c < CPC; ++c) {
        float v = act ? xb[(size_t)c * HW + t] : 0.f;
        xs[t * XSTR + c] = v;
    }
    __syncthreads();
    {
        int c = t & 31, seg = t >> 5;
        float s = 0.f;
        #pragma unroll 8
        for (int i = 0; i < 32; ++i) s += xs[(seg * 32 + i) * XSTR + c];
        psum[seg][c] = s;
    }
    float acc[NTAP];
    #pragma unroll
    for (int n = 0; n < NTAP; ++n) acc[n] = 0.f;
    #pragma unroll 4
    for (int c = 0; c < CPC; ++c) {
        float xv = xs[t * XSTR + c];
        #pragma unroll
        for (int n = 0; n < NTAP; ++n) acc[n] += xv * wss[n][c];
    }
    if (act) {
        float* pp = partial + ((size_t)((b * NCH + chunk) * NTAP)) * HW + pb * 256 + t;
        #pragma unroll
        for (int n = 0; n < NTAP; ++n) pp[(size_t)n * HW] = acc[n];
    }
    __syncthreads();
    if (t < CPC) {
        float tot = 0.f;
        #pragma unroll
        for (int seg = 0; seg < 8; ++seg) tot += psum[seg][t];
        poolpart[((size_t)((b * NCH + chunk) * PBLK + pb)) * CPC + t] = tot;
    }
}

// ============ K2: multi-role — blocks 0..63: MLP+cf ; blocks 64..167: sf reduce+norm ============
#define MLPBLK (BB*NCH)               // 64
#define W2CHUNK (CPC*NTAP*MIDN)       // 14688 floats per 32-channel chunk
__global__ __launch_bounds__(256) void k_mlp_sfB(const float* __restrict__ poolpart,
                                                 const float* __restrict__ w1,
                                                 const float* __restrict__ b1,
                                                 const float* __restrict__ w2,
                                                 const float* __restrict__ b2,
                                                 const float* __restrict__ fn_std,
                                                 const float* __restrict__ partial,
                                                 const float* __restrict__ bs,
                                                 float* __restrict__ cf,
                                                 float* __restrict__ sf) {
    __shared__ float smem[W2CHUNK + 256 + 64 + CPC * NTAP];  // 61.2 KB
    float* w2s = smem;                    // [14688]
    float* ps  = smem + W2CHUNK;          // [256]
    float* y1  = ps + 256;                // [64] (51 used)
    float* y2s = y1 + 64;                 // [288]
    int blk = blockIdx.x;
    int t = threadIdx.x;
    if (blk < MLPBLK) {
        int b = blk >> 3, chunk = blk & 7;
        int c0 = chunk * CPC;
        const float4* w2v = (const float4*)(w2 + (size_t)chunk * W2CHUNK);
        float4* w2s4 = (float4*)w2s;
        for (int i = t; i < W2CHUNK / 4; i += 256) w2s4[i] = w2v[i];
        {
            int chunkp = t >> 5, cl = t & 31;
            float s = 0.f;
            const float* pp = poolpart + ((size_t)(b * NCH + chunkp) * PBLK) * CPC + cl;
            #pragma unroll
            for (int pb = 0; pb < PBLK; ++pb) s += pp[pb * CPC];
            ps[t] = s * (1.0f / HW);
        }
        __syncthreads();
        if (t < MIDN) {
            float acc = b1[t];
            const float* wr = w1 + t * CC;
            for (int c2 = 0; c2 < CC; ++c2) acc += ps[c2] * wr[c2];
            y1[t] = fmaxf(acc, 0.f);
        }
        __syncthreads();
        #pragma unroll
        for (int base = 0; base < 512; base += 256) {
            int idx = base + t;                       // idx = cl*9+q
            if (idx < CPC * NTAP) {
                float acc = b2[c0 * NTAP + idx];
                const float* r = w2s + idx * MIDN;
                #pragma unroll 3
                for (int m = 0; m < MIDN; ++m) acc += y1[m] * r[m];
                y2s[idx] = acc;
            }
        }
        __syncthreads();
        if (t < CPC) {
            int c = c0 + t;
            float y2[NTAP];
            #pragma unroll
            for (int q = 0; q < NTAP; ++q) y2[q] = y2s[t * NTAP + q];
            float mean = 0.f;
            #pragma unroll
            for (int q = 0; q < NTAP; ++q) mean += y2[q];
            mean *= (1.f / NTAP);
            float var = 0.f;
            #pragma unroll
            for (int q = 0; q < NTAP; ++q) { float d = y2[q] - mean; var += d * d; }
            float inv = 1.f / (sqrtf(var * (1.f / (NTAP - 1))) + 1e-10f);
            #pragma unroll
            for (int q = 0; q < NTAP; ++q) {
                int idx = c * NTAP + q;
                cf[(size_t)b * CKK + idx] = (y2[q] - mean) * inv * fn_std[idx];
            }
        }
    } else {
        int sblk = blk - MLPBLK;                 // 0..103
        int b = sblk / PBLK, pb = sblk % PBLK;
        int p = pb * 256 + t;
        if (p >= HW) return;
        float acc[NTAP];
        #pragma unroll
        for (int n = 0; n < NTAP; ++n) acc[n] = bs[n];
        const float* pp = partial + ((size_t)(b * NCH)) * NTAP * HW + p;
        for (int chunk = 0; chunk < NCH; ++chunk)
            #pragma unroll
            for (int n = 0; n < NTAP; ++n)
                acc[n] += pp[((size_t)(chunk * NTAP + n)) * HW];
        float mean = 0.f;
        #pragma unroll
        for (int n = 0; n < NTAP; ++n) mean += acc[n];
        mean *= (1.f / NTAP);
        float var = 0.f;
        #pragma unroll
        for (int n = 0; n < NTAP; ++n) { float d = acc[n] - mean; var += d * d; }
        float inv = 0.47140452079103173f /       // GAIN/K = sqrt(2)/3
                    (sqrtf(var * (1.f / (NTAP - 1))) + 1e-10f);
        #pragma unroll
        for (int n = 0; n < NTAP; ++n)
            sf[((size_t)(b * NTAP + n)) * HW + p] = (acc[n] - mean) * inv;
    }
}

// ============ K3: DDF apply — NCPB=4 channels per 512-thread block ============
// grid: BB*CC/NCPB = 512 blocks = 2 blocks/CU; LDS 53.8 KB -> 2 blocks/CU,
// 16 waves/CU (same occupancy as R6's NCPB=2 config, half the sf traffic).
__global__ __launch_bounds__(512) void k_ddf(const float* __restrict__ x,
                                             const float* __restrict__ cf,
                                             const float* __restrict__ sf,
                                             float* __restrict__ out) {
    int blk = blockIdx.x;
    int b = blk / (CC / NCPB), cg = blk % (CC / NCPB);
    int c0 = cg * NCPB;
    int t = threadIdx.x;
    __shared__ float xt[NCPB][TILE];
    for (int idx = t; idx < NCPB * TILE; idx += 512) ((float*)xt)[idx] = 0.f;
    __syncthreads();
    // stage 4 contiguous planes with float4 loads (NCPB*HW/4 = 3136 float4s)
    const float4* xp4 = (const float4*)(x + ((size_t)(b * CC + c0)) * HW);
    for (int i4 = t; i4 < NCPB * HW / 4; i4 += 512) {
        float4 v = xp4[i4];
        int k = i4 / (HW / 4);                 // plane
        int rem4 = i4 - k * (HW / 4);          // float4 index within plane
        int r = rem4 / (WW / 4);               // row
        int col = 4 * (rem4 - r * (WW / 4));   // col (multiple of 4)
        float* d = &xt[k][(r + 1) * 58 + col + 1];
        d[0] = v.x; d[1] = v.y; d[2] = v.z; d[3] = v.w;
    }
    float cf9[NCPB][NTAP];
    const float* cfp = cf + (size_t)b * CKK + c0 * NTAP;
    #pragma unroll
    for (int k = 0; k < NCPB; ++k)
        #pragma unroll
        for (int n = 0; n < NTAP; ++n) cf9[k][n] = cfp[k * NTAP + n];
    __syncthreads();
    const float* sfb = sf + (size_t)b * NTAP * HW;
    float* op = out + ((size_t)(b * CC + c0)) * HW;
    for (int idx = t; idx < HW; idx += 512) {
        int i = idx / WW, j = idx - i * WW;
        float s9[NTAP];
        #pragma unroll
        for (int n = 0; n < NTAP; ++n) s9[n] = sfb[(size_t)n * HW + idx];
        float acc[NCPB];
        #pragma unroll
        for (int k = 0; k < NCPB; ++k) acc[k] = 0.f;
        #pragma unroll
        for (int u = 0; u < KK; ++u)
            #pragma unroll
            for (int v = 0; v < KK; ++v) {
                int n = u * KK + v;
                int o = (i + u) * 58 + (j + v);
                #pragma unroll
                for (int k = 0; k < NCPB; ++k)
                    acc[k] += xt[k][o] * (cf9[k][n] * s9[n]);
            }
        #pragma unroll
        for (int k = 0; k < NCPB; ++k) op[(size_t)k * HW + idx] = acc[k];
    }
}

extern "C" void kernel_launch(void* const* d_in, const int* in_sizes, int n_in,
                              void* d_out, int out_size, void* d_ws, size_t ws_size,
                              hipStream_t stream) {
    const float* x      = (const float*)d_in[0];
    const float* w1     = (const float*)d_in[1];
    const float* b1     = (const float*)d_in[2];
    const float* w2     = (const float*)d_in[3];
    const float* b2     = (const float*)d_in[4];
    const float* ws     = (const float*)d_in[5];
    const float* bs     = (const float*)d_in[6];
    const float* fn_std = (const float*)d_in[7];
    float* out = (float*)d_out;

    float* wsf      = (float*)d_ws;
    float* cf       = wsf;                         // BB*CKK           = 18432
    float* sf       = cf + 18432;                  // BB*NTAP*HW       = 225792
    float* poolpart = sf + 225792;                 // BB*NCH*PBLK*CPC  = 26624
    float* partial  = poolpart + 26624;            // BB*NCH*NTAP*HW   = 1806336

    k_sfpool<<<BB * NCH * PBLK, 256, 0, stream>>>(x, ws, partial, poolpart);
    k_mlp_sfB<<<MLPBLK + BB * PBLK, 256, 0, stream>>>(poolpart, w1, b1, w2, b2,
                                                      fn_std, partial, bs, cf, sf);
    k_ddf<<<BB * (CC / NCPB), 512, 0, stream>>>(x, cf, sf, out);
}